// Round 5
// baseline (157.778 us; speedup 1.0000x reference)
//
#include <hip/hip_runtime.h>
#include <math.h>

// ---------------------------------------------------------------------------
// GCN: 3x GCNConv (linear) -> mean pool -> linear -> sigmoid.
// Linear-collapse identity (absmax 0.0 through R4):
//   h3 @ lin_w = A(A(A(X u) + s2) + s1) + s0,  u = W1W2W3 lin_w.
// R4 profile: gather/deg passes run 391 blocks (1.5/CU) -> latency-bound on
// random L2 gin reads with no TLP. R5: segment each bucket x8 (3128 blocks),
// slice-blocks write LDS partials non-atomically to a 3.2MB slab; streaming
// node epilogue sums 8 partials. No device atomics.
// ---------------------------------------------------------------------------

#define SHIFT      8
#define BSZ        256         // nodes per bucket = 1<<SHIFT (== blockDim)
#define NB_SCAT    256         // blocks for hist/scatter phases
#define SCAN_CHUNK 2048
#define PNODES     1024        // nodes per pool block
#define ROWMASK    0x1FFFFu    // 17 bits for row id (n < 131072)
#define SEG        8           // slices per bucket in gather passes
#define SEGSH      3

__global__ void coeffs_kernel(const float* __restrict__ W1, const float* __restrict__ b1,
                              const float* __restrict__ W2, const float* __restrict__ b2,
                              const float* __restrict__ W3, const float* __restrict__ b3,
                              const float* __restrict__ lin_w, const float* __restrict__ lin_b,
                              float* __restrict__ coeff,
                              float* __restrict__ sums, float* __restrict__ cnt, int ngraphs) {
    for (int i = threadIdx.x; i < ngraphs; i += blockDim.x) { sums[i] = 0.f; cnt[i] = 0.f; }
    if (threadIdx.x == 0) {
        float w3l[16], w2l[16];
        for (int i = 0; i < 16; ++i) {
            float s = 0.f;
            for (int j = 0; j < 16; ++j) s += W3[i * 16 + j] * lin_w[j];
            w3l[i] = s;
        }
        for (int i = 0; i < 16; ++i) {
            float s = 0.f;
            for (int j = 0; j < 16; ++j) s += W2[i * 16 + j] * w3l[j];
            w2l[i] = s;
        }
        for (int i = 0; i < 4; ++i) {
            float s = 0.f;
            for (int j = 0; j < 16; ++j) s += W1[i * 16 + j] * w2l[j];
            coeff[i] = s;
        }
        float s2 = 0.f, s1 = 0.f, s0 = 0.f;
        for (int j = 0; j < 16; ++j) {
            s2 += b1[j] * w2l[j];
            s1 += b2[j] * w3l[j];
            s0 += b3[j] * lin_w[j];
        }
        coeff[4] = s2; coeff[5] = s1; coeff[6] = s0; coeff[7] = lin_b[0];
    }
}

// ---- Phase A: per-block histogram of col>>SHIFT. M layout: [bin][block].
__global__ void hist_kernel(const int* __restrict__ col, int E, int tile, int nbuck,
                            unsigned* __restrict__ M) {
    extern __shared__ unsigned h[];
    for (int i = threadIdx.x; i < nbuck; i += blockDim.x) h[i] = 0;
    __syncthreads();
    int b = blockIdx.x;
    int s = b * tile, e = min(s + tile, E);          // s is multiple of 4 (tile rounded)
    if (s < e) {
        int nq = (e - s) >> 2;
        const int4* c4 = (const int4*)(col + s);
        for (int q = threadIdx.x; q < nq; q += blockDim.x) {
            int4 c = c4[q];
            atomicAdd(&h[((unsigned)c.x) >> SHIFT], 1u);
            atomicAdd(&h[((unsigned)c.y) >> SHIFT], 1u);
            atomicAdd(&h[((unsigned)c.z) >> SHIFT], 1u);
            atomicAdd(&h[((unsigned)c.w) >> SHIFT], 1u);
        }
        for (int k = s + (nq << 2) + threadIdx.x; k < e; k += blockDim.x)
            atomicAdd(&h[((unsigned)col[k]) >> SHIFT], 1u);
    }
    __syncthreads();
    for (int i = threadIdx.x; i < nbuck; i += blockDim.x)
        M[(size_t)i * NB_SCAT + b] = h[i];
}

// ---- exclusive scan over M (nbuck*NB_SCAT elems), 3-kernel hierarchy
__global__ void scan1_kernel(const unsigned* __restrict__ M, unsigned* __restrict__ part,
                             int total, int chunk) {
    __shared__ unsigned sdata[256];
    int b = blockIdx.x;
    int s = b * chunk, e = min(s + chunk, total);
    unsigned sum = 0;
    for (int k = s + threadIdx.x; k < e; k += blockDim.x) sum += M[k];
    sdata[threadIdx.x] = sum;
    __syncthreads();
    for (int off = 128; off > 0; off >>= 1) {
        if (threadIdx.x < off) sdata[threadIdx.x] += sdata[threadIdx.x + off];
        __syncthreads();
    }
    if (threadIdx.x == 0) part[b] = sdata[0];
}

__global__ void scan2_kernel(unsigned* __restrict__ part, int np) {
    if (threadIdx.x == 0 && blockIdx.x == 0) {
        unsigned run = 0;
        for (int i = 0; i < np; ++i) { unsigned v = part[i]; part[i] = run; run += v; }
    }
}

__global__ void scan3_kernel(unsigned* __restrict__ M, const unsigned* __restrict__ part,
                             int total, int chunk) {
    __shared__ unsigned ts[256];
    int b = blockIdx.x;
    int s = b * chunk;
    const int per = SCAN_CHUNK / 256;      // 8
    unsigned v[per];
    unsigned sum = 0;
    int base = s + threadIdx.x * per;
    for (int j = 0; j < per; ++j) {
        unsigned x = (base + j < total) ? M[base + j] : 0u;
        v[j] = sum; sum += x;
    }
    ts[threadIdx.x] = sum;
    __syncthreads();
    for (int off = 1; off < 256; off <<= 1) {
        unsigned t = (threadIdx.x >= (unsigned)off) ? ts[threadIdx.x - off] : 0u;
        __syncthreads();
        ts[threadIdx.x] += t;
        __syncthreads();
    }
    unsigned texcl = (threadIdx.x == 0) ? 0u : ts[threadIdx.x - 1];
    unsigned pb = part[b];
    for (int j = 0; j < per; ++j)
        if (base + j < total) M[base + j] = pb + texcl + v[j];
}

// ---- Phase B: scatter into buckets; pack row(17b) | col_low(8b)<<17
__global__ void scatter_kernel(const int* __restrict__ row, const int* __restrict__ col,
                               int E, int tile, int nbuck, const unsigned* __restrict__ M,
                               unsigned* __restrict__ out) {
    extern __shared__ unsigned base[];
    int b = blockIdx.x;
    for (int i = threadIdx.x; i < nbuck; i += blockDim.x)
        base[i] = M[(size_t)i * NB_SCAT + b];
    __syncthreads();
    int s = b * tile, e = min(s + tile, E);
    if (s < e) {
        int nq = (e - s) >> 2;
        const int4* r4 = (const int4*)(row + s);
        const int4* c4 = (const int4*)(col + s);
        for (int q = threadIdx.x; q < nq; q += blockDim.x) {
            int4 r = r4[q];
            int4 c = c4[q];
            unsigned p0 = atomicAdd(&base[((unsigned)c.x) >> SHIFT], 1u);
            unsigned p1 = atomicAdd(&base[((unsigned)c.y) >> SHIFT], 1u);
            unsigned p2 = atomicAdd(&base[((unsigned)c.z) >> SHIFT], 1u);
            unsigned p3 = atomicAdd(&base[((unsigned)c.w) >> SHIFT], 1u);
            out[p0] = (unsigned)r.x | (((unsigned)c.x & (BSZ - 1)) << 17);
            out[p1] = (unsigned)r.y | (((unsigned)c.y & (BSZ - 1)) << 17);
            out[p2] = (unsigned)r.z | (((unsigned)c.z & (BSZ - 1)) << 17);
            out[p3] = (unsigned)r.w | (((unsigned)c.w & (BSZ - 1)) << 17);
        }
        for (int k = s + (nq << 2) + threadIdx.x; k < e; k += blockDim.x) {
            unsigned c = (unsigned)col[k];
            unsigned pos = atomicAdd(&base[c >> SHIFT], 1u);
            out[pos] = (unsigned)row[k] | ((c & (BSZ - 1)) << 17);
        }
    }
}

// ---- segmented degree count: block (b,s) counts its slice into LDS, writes partial
__global__ void degseg_kernel(const unsigned* __restrict__ buck, const unsigned* __restrict__ M,
                              int nbuck, int E, float* __restrict__ partial) {
    __shared__ float acc[BSZ];
    int b = blockIdx.x >> SEGSH;
    int sg = blockIdx.x & (SEG - 1);
    acc[threadIdx.x] = 0.f;
    __syncthreads();
    unsigned start = M[(size_t)b * NB_SCAT];
    unsigned end = (b + 1 < nbuck) ? M[(size_t)(b + 1) * NB_SCAT] : (unsigned)E;
    unsigned len = end - start;
    unsigned s0 = start + (unsigned)(((unsigned long long)len * sg) >> SEGSH);
    unsigned s1 = start + (unsigned)(((unsigned long long)len * (sg + 1)) >> SEGSH);
    unsigned sa = (s0 + 3u) & ~3u;
    if (sa > s1) sa = s1;
    if (s0 + threadIdx.x < sa)
        atomicAdd(&acc[buck[s0 + threadIdx.x] >> 17], 1.0f);
    unsigned nq = (s1 - sa) >> 2;
    const uint4* bq = (const uint4*)(buck + sa);
    for (unsigned q = threadIdx.x; q < nq; q += blockDim.x) {
        uint4 w = bq[q];
        atomicAdd(&acc[w.x >> 17], 1.0f);
        atomicAdd(&acc[w.y >> 17], 1.0f);
        atomicAdd(&acc[w.z >> 17], 1.0f);
        atomicAdd(&acc[w.w >> 17], 1.0f);
    }
    for (unsigned k = sa + (nq << 2) + threadIdx.x; k < s1; k += blockDim.x)
        atomicAdd(&acc[buck[k] >> 17], 1.0f);
    __syncthreads();
    partial[((size_t)sg * nbuck + b) * BSZ + threadIdx.x] = acc[threadIdx.x];
}

// ---- node0 epilogue: dinv = rsqrt(sum partials + 1); g0 = dinv * (x.u)
__global__ void node0_kernel(const float* __restrict__ partial, int nbuck,
                             const float* __restrict__ x, const float* __restrict__ coeff,
                             float* __restrict__ dinv, float* __restrict__ g, int n) {
    int node = blockIdx.x * blockDim.x + threadIdx.x;
    if (node >= n) return;
    size_t slot = (size_t)blockIdx.x * BSZ + threadIdx.x;   // == node (BSZ==blockDim)
    float deg = 1.0f;
    for (int sg = 0; sg < SEG; ++sg)
        deg += partial[(size_t)sg * nbuck * BSZ + slot];
    float d = rsqrtf(deg);
    dinv[node] = d;
    float4 xv = ((const float4*)x)[node];
    float t0 = xv.x * coeff[0] + xv.y * coeff[1] + xv.z * coeff[2] + xv.w * coeff[3];
    g[node] = d * t0;
}

// ---- segmented gather: block (b,s) accumulates gin[row] for its slice
__global__ void gatherseg_kernel(const unsigned* __restrict__ buck, const unsigned* __restrict__ M,
                                 int nbuck, int E, const float* __restrict__ gin,
                                 float* __restrict__ partial) {
    __shared__ float acc[BSZ];
    int b = blockIdx.x >> SEGSH;
    int sg = blockIdx.x & (SEG - 1);
    acc[threadIdx.x] = 0.f;
    __syncthreads();
    unsigned start = M[(size_t)b * NB_SCAT];
    unsigned end = (b + 1 < nbuck) ? M[(size_t)(b + 1) * NB_SCAT] : (unsigned)E;
    unsigned len = end - start;
    unsigned s0 = start + (unsigned)(((unsigned long long)len * sg) >> SEGSH);
    unsigned s1 = start + (unsigned)(((unsigned long long)len * (sg + 1)) >> SEGSH);
    unsigned sa = (s0 + 3u) & ~3u;
    if (sa > s1) sa = s1;
    if (s0 + threadIdx.x < sa) {
        unsigned w = buck[s0 + threadIdx.x];
        atomicAdd(&acc[w >> 17], gin[w & ROWMASK]);
    }
    unsigned nq = (s1 - sa) >> 2;
    const uint4* bq = (const uint4*)(buck + sa);
    for (unsigned q = threadIdx.x; q < nq; q += blockDim.x) {
        uint4 w = bq[q];
        float a0 = gin[w.x & ROWMASK];     // 4 independent gathers in flight
        float a1 = gin[w.y & ROWMASK];
        float a2 = gin[w.z & ROWMASK];
        float a3 = gin[w.w & ROWMASK];
        atomicAdd(&acc[w.x >> 17], a0);
        atomicAdd(&acc[w.y >> 17], a1);
        atomicAdd(&acc[w.z >> 17], a2);
        atomicAdd(&acc[w.w >> 17], a3);
    }
    for (unsigned k = sa + (nq << 2) + threadIdx.x; k < s1; k += blockDim.x) {
        unsigned w = buck[k];
        atomicAdd(&acc[w >> 17], gin[w & ROWMASK]);
    }
    __syncthreads();
    partial[((size_t)sg * nbuck + b) * BSZ + threadIdx.x] = acc[threadIdx.x];
}

// ---- node epilogue: t = dinv*(sum partials + gin) + s; gout = lastPass ? t : dinv*t
__global__ void nodefin_kernel(const float* __restrict__ partial, int nbuck,
                               const float* __restrict__ dinv, const float* __restrict__ gin,
                               float* __restrict__ gout, const float* __restrict__ coeff,
                               int sidx, int n, int lastPass) {
    int node = blockIdx.x * blockDim.x + threadIdx.x;
    if (node >= n) return;
    size_t slot = (size_t)blockIdx.x * BSZ + threadIdx.x;
    float a = 0.f;
    for (int sg = 0; sg < SEG; ++sg)
        a += partial[(size_t)sg * nbuck * BSZ + slot];
    float d = dinv[node];
    float t = d * (a + gin[node]) + coeff[sidx];
    gout[node] = lastPass ? t : d * t;
}

// ---- segmented mean-pool using SORTED batch: LDS slots + sparse atomics
__global__ void pool_kernel(const float* __restrict__ t3, const int* __restrict__ batch,
                            float* __restrict__ sums, float* __restrict__ cnt, int n) {
    __shared__ float ls[1024];
    __shared__ float lc[1024];
    int s = blockIdx.x * PNODES, e = min(s + PNODES, n);
    if (s >= e) return;
    int bFirst = batch[s];
    int bLast  = batch[e - 1];
    int range = bLast - bFirst + 1;
    if (range <= 1024) {
        for (int i = threadIdx.x; i < range; i += blockDim.x) { ls[i] = 0.f; lc[i] = 0.f; }
        __syncthreads();
        for (int k = s + threadIdx.x; k < e; k += blockDim.x) {
            int bb = batch[k] - bFirst;
            atomicAdd(&ls[bb], t3[k]);
            atomicAdd(&lc[bb], 1.0f);
        }
        __syncthreads();
        for (int i = threadIdx.x; i < range; i += blockDim.x) {
            if (lc[i] != 0.f) {
                atomicAdd(&sums[bFirst + i], ls[i]);
                atomicAdd(&cnt[bFirst + i], lc[i]);
            }
        }
    } else {  // defensive fallback (unreachable for ngraphs<=1024)
        for (int k = s + threadIdx.x; k < e; k += blockDim.x) {
            atomicAdd(&sums[batch[k]], t3[k]);
            atomicAdd(&cnt[batch[k]], 1.0f);
        }
    }
}

__global__ void final_kernel(const float* __restrict__ sums, const float* __restrict__ cnt,
                             const float* __restrict__ coeff, float* __restrict__ out,
                             int ngraphs) {
    int i = blockIdx.x * blockDim.x + threadIdx.x;
    if (i < ngraphs) {
        float m = sums[i] / fmaxf(cnt[i], 1.0f) + coeff[7];
        out[i] = 1.0f / (1.0f + expf(-m));
    }
}

// ======================= R1 fallback (atomic path) =========================
__global__ void fb_init_kernel(float* __restrict__ deg, float* __restrict__ sums,
                               float* __restrict__ cnt, int n, int ngraphs) {
    int i = blockIdx.x * blockDim.x + threadIdx.x;
    int stride = gridDim.x * blockDim.x;
    for (int k = i; k < n; k += stride) deg[k] = 1.0f;
    for (int k = i; k < ngraphs; k += stride) { sums[k] = 0.f; cnt[k] = 0.f; }
}
__global__ void fb_deg_kernel(const int* __restrict__ col, float* __restrict__ deg, int E) {
    int i = blockIdx.x * blockDim.x + threadIdx.x;
    int stride = gridDim.x * blockDim.x;
    for (int k = i; k < E; k += stride) atomicAdd(&deg[col[k]], 1.0f);
}
__global__ void fb_node0_kernel(const float* __restrict__ x, const float* __restrict__ coeff,
                                float* __restrict__ deg_dinv, float* __restrict__ g,
                                float* __restrict__ acc, int n) {
    int i = blockIdx.x * blockDim.x + threadIdx.x;
    int stride = gridDim.x * blockDim.x;
    for (int k = i; k < n; k += stride) {
        float d = rsqrtf(deg_dinv[k]);
        deg_dinv[k] = d;
        float4 xv = ((const float4*)x)[k];
        float t0 = xv.x * coeff[0] + xv.y * coeff[1] + xv.z * coeff[2] + xv.w * coeff[3];
        g[k] = d * t0;
        acc[k] = 0.f;
    }
}
__global__ void fb_edge_kernel(const int* __restrict__ ei, const float* __restrict__ g,
                               float* __restrict__ acc, int E) {
    int i = blockIdx.x * blockDim.x + threadIdx.x;
    int stride = gridDim.x * blockDim.x;
    for (int k = i; k < E; k += stride) atomicAdd(&acc[ei[E + k]], g[ei[k]]);
}
__global__ void fb_node_kernel(const float* __restrict__ dinv, float* __restrict__ g,
                               float* __restrict__ acc, const float* __restrict__ coeff,
                               int sidx, int n) {
    int i = blockIdx.x * blockDim.x + threadIdx.x;
    int stride = gridDim.x * blockDim.x;
    for (int k = i; k < n; k += stride) {
        float d = dinv[k];
        float t = d * (acc[k] + g[k]) + coeff[sidx];
        g[k] = d * t;
        acc[k] = 0.f;
    }
}
__global__ void fb_pool_kernel(const float* __restrict__ dinv, const float* __restrict__ g,
                               const float* __restrict__ acc, const float* __restrict__ coeff,
                               const int* __restrict__ batch, float* __restrict__ sums,
                               float* __restrict__ cnt, int n) {
    int i = blockIdx.x * blockDim.x + threadIdx.x;
    int stride = gridDim.x * blockDim.x;
    for (int k = i; k < n; k += stride) {
        float d = dinv[k];
        float t3 = d * (acc[k] + g[k]) + coeff[6];
        int b = batch[k];
        atomicAdd(&sums[b], t3);
        atomicAdd(&cnt[b], 1.0f);
    }
}
// ===========================================================================

extern "C" void kernel_launch(void* const* d_in, const int* in_sizes, int n_in,
                              void* d_out, int out_size, void* d_ws, size_t ws_size,
                              hipStream_t stream) {
    const float* x     = (const float*)d_in[0];
    const int*   ei    = (const int*)d_in[1];
    const int*   batch = (const int*)d_in[2];
    const float* W1    = (const float*)d_in[3];
    const float* b1    = (const float*)d_in[4];
    const float* W2    = (const float*)d_in[5];
    const float* b2    = (const float*)d_in[6];
    const float* W3    = (const float*)d_in[7];
    const float* b3    = (const float*)d_in[8];
    const float* lin_w = (const float*)d_in[9];
    const float* lin_b = (const float*)d_in[10];

    const int n       = in_sizes[0] / 4;   // 100000
    const int E       = in_sizes[1] / 2;   // 3200000
    const int ngraphs = out_size;          // 1000

    const int nbuck = (n + BSZ - 1) / BSZ; // 391
    const int B = 256;

    size_t npad = ((size_t)n + 255) & ~(size_t)255;
    size_t gpad = ((size_t)ngraphs + 255) & ~(size_t)255;
    size_t mlen = (size_t)nbuck * NB_SCAT;
    size_t plen = (size_t)SEG * nbuck * BSZ;
    int total   = (int)mlen;
    int nchunks = (total + SCAN_CHUNK - 1) / SCAN_CHUNK;

    size_t need = (256 + mlen + 1024 + (size_t)E + plen + 3 * npad + 2 * gpad) * 4;

    float* ws   = (float*)d_ws;
    float* coeff = ws;                                    // 256
    unsigned* M    = (unsigned*)(coeff + 256);            // mlen
    unsigned* part = M + mlen;                            // <=1024
    unsigned* buck = part + 1024;                         // E (16B aligned)
    float* partial = (float*)(buck + E);                  // plen
    float* dinv  = partial + plen;                        // npad
    float* gA    = dinv + npad;                           // npad
    float* gB    = gA + npad;                             // npad
    float* sums  = gB + npad;                             // gpad
    float* cnt   = sums + gpad;                           // gpad

    if (ws_size < need) {
        // -------- fallback: R1 atomic path (needs ~1.3 MB) --------
        float* fcoeff = ws;
        float* deg = fcoeff + 256;
        float* g   = deg + npad;
        float* acc = g + npad;
        float* fsums = acc + npad;
        float* fcnt  = fsums + gpad;
        int nodeBlocks = (n + B - 1) / B;
        int edgeBlocks = (E + B - 1) / B;
        coeffs_kernel<<<1, 64, 0, stream>>>(W1, b1, W2, b2, W3, b3, lin_w, lin_b, fcoeff,
                                            fsums, fcnt, ngraphs);
        fb_init_kernel<<<nodeBlocks, B, 0, stream>>>(deg, fsums, fcnt, n, ngraphs);
        fb_deg_kernel<<<edgeBlocks, B, 0, stream>>>(ei + E, deg, E);
        fb_node0_kernel<<<nodeBlocks, B, 0, stream>>>(x, fcoeff, deg, g, acc, n);
        fb_edge_kernel<<<edgeBlocks, B, 0, stream>>>(ei, g, acc, E);
        fb_node_kernel<<<nodeBlocks, B, 0, stream>>>(deg, g, acc, fcoeff, 4, n);
        fb_edge_kernel<<<edgeBlocks, B, 0, stream>>>(ei, g, acc, E);
        fb_node_kernel<<<nodeBlocks, B, 0, stream>>>(deg, g, acc, fcoeff, 5, n);
        fb_edge_kernel<<<edgeBlocks, B, 0, stream>>>(ei, g, acc, E);
        fb_pool_kernel<<<nodeBlocks, B, 0, stream>>>(deg, g, acc, fcoeff, batch, fsums, fcnt, n);
        final_kernel<<<(ngraphs + B - 1) / B, B, 0, stream>>>(fsums, fcnt, fcoeff, (float*)d_out, ngraphs);
        return;
    }

    // tile rounded to multiple of 4 so every block's base is 16B-aligned
    int tile = (((E + NB_SCAT - 1) / NB_SCAT) + 3) & ~3;
    size_t ldsHist = (size_t)nbuck * sizeof(unsigned);
    int segBlocks = nbuck << SEGSH;

    coeffs_kernel<<<1, B, 0, stream>>>(W1, b1, W2, b2, W3, b3, lin_w, lin_b, coeff,
                                       sums, cnt, ngraphs);

    hist_kernel<<<NB_SCAT, B, ldsHist, stream>>>(ei + E, E, tile, nbuck, M);
    scan1_kernel<<<nchunks, B, 0, stream>>>(M, part, total, SCAN_CHUNK);
    scan2_kernel<<<1, 64, 0, stream>>>(part, nchunks);
    scan3_kernel<<<nchunks, B, 0, stream>>>(M, part, total, SCAN_CHUNK);
    scatter_kernel<<<NB_SCAT, B, ldsHist, stream>>>(ei, ei + E, E, tile, nbuck, M, buck);

    degseg_kernel<<<segBlocks, B, 0, stream>>>(buck, M, nbuck, E, partial);
    node0_kernel<<<nbuck, B, 0, stream>>>(partial, nbuck, x, coeff, dinv, gA, n);

    gatherseg_kernel<<<segBlocks, B, 0, stream>>>(buck, M, nbuck, E, gA, partial);
    nodefin_kernel<<<nbuck, B, 0, stream>>>(partial, nbuck, dinv, gA, gB, coeff, 4, n, 0);
    gatherseg_kernel<<<segBlocks, B, 0, stream>>>(buck, M, nbuck, E, gB, partial);
    nodefin_kernel<<<nbuck, B, 0, stream>>>(partial, nbuck, dinv, gB, gA, coeff, 5, n, 0);
    gatherseg_kernel<<<segBlocks, B, 0, stream>>>(buck, M, nbuck, E, gA, partial);
    nodefin_kernel<<<nbuck, B, 0, stream>>>(partial, nbuck, dinv, gA, gB, coeff, 6, n, 1);

    pool_kernel<<<(n + PNODES - 1) / PNODES, B, 0, stream>>>(gB, batch, sums, cnt, n);

    final_kernel<<<(ngraphs + B - 1) / B, B, 0, stream>>>(sums, cnt, coeff, (float*)d_out, ngraphs);
}

// Round 6
// 144.365 us; speedup vs baseline: 1.0929x; 1.0929x over previous
//
#include <hip/hip_runtime.h>
#include <math.h>

// ---------------------------------------------------------------------------
// GCN: 3x GCNConv (linear) -> mean pool -> linear -> sigmoid.
// Linear-collapse identity (absmax 0.0 through R5):
//   h3 @ lin_w = A(A(A(X u) + s2) + s1) + s0,  u = W1W2W3 lin_w.
// R5 lesson: R4 (14 dispatches) and R5 (16 dispatches, +8x gather TLP) timed
// IDENTICAL (157.75 vs 157.78us) -> aggregate dominated by inter-dispatch
// overhead (~4-6us x 16 serialized boundaries), not by the phases.
// R6: dispatch count 16 -> 8. coeffs+zero fused into hist block0 (and made
// lane-parallel); scan2/3 replaced by per-scatter-block LDS scan of bin
// totals; gather+node fused (no partial slab); pool fused into pass 3.
// Bucket = 128 nodes (nbuck=782 ~ 3 blocks/CU).
// ---------------------------------------------------------------------------

#define SHIFT      7
#define BSZ        128         // nodes per bucket = 1<<SHIFT
#define NB_SCAT    256         // blocks for hist/scatter phases
#define ROWMASK    0x1FFFFu    // 17 bits for row id (n < 131072)
#define PSLOTS     64          // LDS pool slots per pass-3 block

// ---- K1: histogram of col>>SHIFT (M[j][bin]) + coeffs + sums/cnt zero ----
__global__ void hist_kernel(const int* __restrict__ col, int E, int tile, int nbuck,
                            unsigned* __restrict__ M,
                            const float* __restrict__ W1, const float* __restrict__ b1,
                            const float* __restrict__ W2, const float* __restrict__ b2,
                            const float* __restrict__ W3, const float* __restrict__ b3,
                            const float* __restrict__ lin_w, const float* __restrict__ lin_b,
                            float* __restrict__ coeff,
                            float* __restrict__ sums, float* __restrict__ cnt, int ngraphs) {
    extern __shared__ unsigned h[];
    __shared__ float w3l[16], w2l[16];
    int t = threadIdx.x;
    for (int i = t; i < nbuck; i += blockDim.x) h[i] = 0;
    if (blockIdx.x == 0) {
        for (int i = t; i < ngraphs; i += blockDim.x) { sums[i] = 0.f; cnt[i] = 0.f; }
        if (t < 16) {
            float s = 0.f;
            for (int j = 0; j < 16; ++j) s += W3[t * 16 + j] * lin_w[j];
            w3l[t] = s;
        }
    }
    __syncthreads();
    if (blockIdx.x == 0 && t < 16) {
        float s = 0.f;
        for (int j = 0; j < 16; ++j) s += W2[t * 16 + j] * w3l[j];
        w2l[t] = s;
    }
    __syncthreads();
    if (blockIdx.x == 0) {
        if (t < 4) {
            float s = 0.f;
            for (int j = 0; j < 16; ++j) s += W1[t * 16 + j] * w2l[j];
            coeff[t] = s;
        } else if (t == 4) {
            float s = 0.f;
            for (int j = 0; j < 16; ++j) s += b1[j] * w2l[j];
            coeff[4] = s;
        } else if (t == 5) {
            float s = 0.f;
            for (int j = 0; j < 16; ++j) s += b2[j] * w3l[j];
            coeff[5] = s;
        } else if (t == 6) {
            float s = 0.f;
            for (int j = 0; j < 16; ++j) s += b3[j] * lin_w[j];
            coeff[6] = s;
        } else if (t == 7) {
            coeff[7] = lin_b[0];
        }
    }
    // histogram
    int b = blockIdx.x;
    int s = b * tile, e = min(s + tile, E);          // s multiple of 4
    if (s < e) {
        int nq = (e - s) >> 2;
        const int4* c4 = (const int4*)(col + s);
        for (int q = t; q < nq; q += blockDim.x) {
            int4 c = c4[q];
            atomicAdd(&h[((unsigned)c.x) >> SHIFT], 1u);
            atomicAdd(&h[((unsigned)c.y) >> SHIFT], 1u);
            atomicAdd(&h[((unsigned)c.z) >> SHIFT], 1u);
            atomicAdd(&h[((unsigned)c.w) >> SHIFT], 1u);
        }
        for (int k = s + (nq << 2) + t; k < e; k += blockDim.x)
            atomicAdd(&h[((unsigned)col[k]) >> SHIFT], 1u);
    }
    __syncthreads();
    for (int i = t; i < nbuck; i += blockDim.x)
        M[(size_t)b * nbuck + i] = h[i];
}

// ---- K2: per-bin exclusive scan over the NB_SCAT block counts ----
__global__ void scanA_kernel(unsigned* __restrict__ M, unsigned* __restrict__ binTotal,
                             int nbuck) {
    __shared__ unsigned sc[NB_SCAT];
    int b = blockIdx.x;
    int t = threadIdx.x;
    unsigned v = M[(size_t)t * nbuck + b];
    sc[t] = v;
    __syncthreads();
    for (int off = 1; off < NB_SCAT; off <<= 1) {
        unsigned u = (t >= off) ? sc[t - off] : 0u;
        __syncthreads();
        sc[t] += u;
        __syncthreads();
    }
    M[(size_t)t * nbuck + b] = sc[t] - v;     // exclusive within bin
    if (t == NB_SCAT - 1) binTotal[b] = sc[t];
}

// ---- K3: scatter into buckets; each block scans binTotal in LDS ----
// pack: row(17b) | col_low(7b)<<17
__global__ void scatter_kernel(const int* __restrict__ row, const int* __restrict__ col,
                               int E, int tile, int nbuck,
                               const unsigned* __restrict__ M,
                               const unsigned* __restrict__ binTotal,
                               unsigned* __restrict__ bstart,
                               unsigned* __restrict__ out) {
    extern __shared__ unsigned lds[];        // bb[nbuck] | base[nbuck] | tsum[256]
    unsigned* bb   = lds;
    unsigned* base = lds + nbuck;
    unsigned* tsum = lds + 2 * nbuck;
    int t = threadIdx.x;
    int C = (nbuck + NB_SCAT - 1) >> 8;      // elems per thread (<=8 by host guard)
    unsigned lv[8];
    unsigned ls = 0;
    for (int k = 0; k < C; ++k) {
        int i = t * C + k;
        unsigned x = (i < nbuck) ? binTotal[i] : 0u;
        lv[k] = ls; ls += x;
    }
    tsum[t] = ls;
    __syncthreads();
    for (int off = 1; off < NB_SCAT; off <<= 1) {
        unsigned u = (t >= off) ? tsum[t - off] : 0u;
        __syncthreads();
        tsum[t] += u;
        __syncthreads();
    }
    unsigned ex = (t == 0) ? 0u : tsum[t - 1];
    for (int k = 0; k < C; ++k) {
        int i = t * C + k;
        if (i < nbuck) bb[i] = ex + lv[k];
    }
    __syncthreads();
    int j = blockIdx.x;
    for (int i = t; i < nbuck; i += blockDim.x)
        base[i] = bb[i] + M[(size_t)j * nbuck + i];
    if (j == 0) {
        for (int i = t; i < nbuck; i += blockDim.x) bstart[i] = bb[i];
        if (t == 0) bstart[nbuck] = (unsigned)E;
    }
    __syncthreads();
    int s = j * tile, e = min(s + tile, E);
    if (s < e) {
        int nq = (e - s) >> 2;
        const int4* r4 = (const int4*)(row + s);
        const int4* c4 = (const int4*)(col + s);
        for (int q = t; q < nq; q += blockDim.x) {
            int4 r = r4[q];
            int4 c = c4[q];
            unsigned p0 = atomicAdd(&base[((unsigned)c.x) >> SHIFT], 1u);
            unsigned p1 = atomicAdd(&base[((unsigned)c.y) >> SHIFT], 1u);
            unsigned p2 = atomicAdd(&base[((unsigned)c.z) >> SHIFT], 1u);
            unsigned p3 = atomicAdd(&base[((unsigned)c.w) >> SHIFT], 1u);
            out[p0] = (unsigned)r.x | (((unsigned)c.x & (BSZ - 1)) << 17);
            out[p1] = (unsigned)r.y | (((unsigned)c.y & (BSZ - 1)) << 17);
            out[p2] = (unsigned)r.z | (((unsigned)c.z & (BSZ - 1)) << 17);
            out[p3] = (unsigned)r.w | (((unsigned)c.w & (BSZ - 1)) << 17);
        }
        for (int k = s + (nq << 2) + t; k < e; k += blockDim.x) {
            unsigned c = (unsigned)col[k];
            unsigned pos = atomicAdd(&base[c >> SHIFT], 1u);
            out[pos] = (unsigned)row[k] | ((c & (BSZ - 1)) << 17);
        }
    }
}

// ---- K4: degree count + node0 epilogue (dinv, g0 = dinv * x.u) ----
__global__ void degnode0_kernel(const unsigned* __restrict__ buck,
                                const unsigned* __restrict__ bstart,
                                const float* __restrict__ x, const float* __restrict__ coeff,
                                float* __restrict__ dinv, float* __restrict__ g, int n) {
    __shared__ float acc[BSZ];
    int b = blockIdx.x;
    acc[threadIdx.x] = 0.f;
    __syncthreads();
    unsigned s = bstart[b], e = bstart[b + 1];
    unsigned sa = (s + 3u) & ~3u;
    if (sa > e) sa = e;
    if (s + threadIdx.x < sa)
        atomicAdd(&acc[buck[s + threadIdx.x] >> 17], 1.0f);
    unsigned nq = (e - sa) >> 2;
    const uint4* bq = (const uint4*)(buck + sa);
    for (unsigned q = threadIdx.x; q < nq; q += blockDim.x) {
        uint4 w = bq[q];
        atomicAdd(&acc[w.x >> 17], 1.0f);
        atomicAdd(&acc[w.y >> 17], 1.0f);
        atomicAdd(&acc[w.z >> 17], 1.0f);
        atomicAdd(&acc[w.w >> 17], 1.0f);
    }
    for (unsigned k = sa + (nq << 2) + threadIdx.x; k < e; k += blockDim.x)
        atomicAdd(&acc[buck[k] >> 17], 1.0f);
    __syncthreads();
    int node = b * BSZ + threadIdx.x;
    if (node < n) {
        float d = rsqrtf(acc[threadIdx.x] + 1.0f);
        dinv[node] = d;
        float4 xv = ((const float4*)x)[node];
        float t0 = xv.x * coeff[0] + xv.y * coeff[1] + xv.z * coeff[2] + xv.w * coeff[3];
        g[node] = d * t0;
    }
}

// ---- K5/K6: gather pass with fused node epilogue ----
__global__ void gather_kernel(const unsigned* __restrict__ buck,
                              const unsigned* __restrict__ bstart,
                              const float* __restrict__ dinv, const float* __restrict__ gin,
                              float* __restrict__ gout, const float* __restrict__ coeff,
                              int sidx, int n) {
    __shared__ float acc[BSZ];
    int b = blockIdx.x;
    acc[threadIdx.x] = 0.f;
    __syncthreads();
    unsigned s = bstart[b], e = bstart[b + 1];
    unsigned sa = (s + 3u) & ~3u;
    if (sa > e) sa = e;
    if (s + threadIdx.x < sa) {
        unsigned w = buck[s + threadIdx.x];
        atomicAdd(&acc[w >> 17], gin[w & ROWMASK]);
    }
    unsigned nq = (e - sa) >> 2;
    const uint4* bq = (const uint4*)(buck + sa);
    for (unsigned q = threadIdx.x; q < nq; q += blockDim.x) {
        uint4 w = bq[q];
        float a0 = gin[w.x & ROWMASK];
        float a1 = gin[w.y & ROWMASK];
        float a2 = gin[w.z & ROWMASK];
        float a3 = gin[w.w & ROWMASK];
        atomicAdd(&acc[w.x >> 17], a0);
        atomicAdd(&acc[w.y >> 17], a1);
        atomicAdd(&acc[w.z >> 17], a2);
        atomicAdd(&acc[w.w >> 17], a3);
    }
    for (unsigned k = sa + (nq << 2) + threadIdx.x; k < e; k += blockDim.x) {
        unsigned w = buck[k];
        atomicAdd(&acc[w >> 17], gin[w & ROWMASK]);
    }
    __syncthreads();
    int node = b * BSZ + threadIdx.x;
    if (node < n) {
        float d = dinv[node];
        float t = d * (acc[threadIdx.x] + gin[node]) + coeff[sidx];
        gout[node] = d * t;
    }
}

// ---- K7: pass 3 gather + fused segmented mean-pool (batch sorted) ----
__global__ void gatherpool_kernel(const unsigned* __restrict__ buck,
                                  const unsigned* __restrict__ bstart,
                                  const float* __restrict__ dinv, const float* __restrict__ gin,
                                  const float* __restrict__ coeff, const int* __restrict__ batch,
                                  float* __restrict__ sums, float* __restrict__ cnt, int n) {
    __shared__ float acc[BSZ];
    __shared__ float ls[PSLOTS], lc[PSLOTS];
    __shared__ int bF;
    int b = blockIdx.x;
    acc[threadIdx.x] = 0.f;
    for (int i = threadIdx.x; i < PSLOTS; i += blockDim.x) { ls[i] = 0.f; lc[i] = 0.f; }
    if (threadIdx.x == 0) bF = batch[b * BSZ];
    __syncthreads();
    unsigned s = bstart[b], e = bstart[b + 1];
    unsigned sa = (s + 3u) & ~3u;
    if (sa > e) sa = e;
    if (s + threadIdx.x < sa) {
        unsigned w = buck[s + threadIdx.x];
        atomicAdd(&acc[w >> 17], gin[w & ROWMASK]);
    }
    unsigned nq = (e - sa) >> 2;
    const uint4* bq = (const uint4*)(buck + sa);
    for (unsigned q = threadIdx.x; q < nq; q += blockDim.x) {
        uint4 w = bq[q];
        float a0 = gin[w.x & ROWMASK];
        float a1 = gin[w.y & ROWMASK];
        float a2 = gin[w.z & ROWMASK];
        float a3 = gin[w.w & ROWMASK];
        atomicAdd(&acc[w.x >> 17], a0);
        atomicAdd(&acc[w.y >> 17], a1);
        atomicAdd(&acc[w.z >> 17], a2);
        atomicAdd(&acc[w.w >> 17], a3);
    }
    for (unsigned k = sa + (nq << 2) + threadIdx.x; k < e; k += blockDim.x) {
        unsigned w = buck[k];
        atomicAdd(&acc[w >> 17], gin[w & ROWMASK]);
    }
    __syncthreads();
    int node = b * BSZ + threadIdx.x;
    if (node < n) {
        float d = dinv[node];
        float t3 = d * (acc[threadIdx.x] + gin[node]) + coeff[6];
        int rb = batch[node] - bF;               // batch sorted -> rb >= 0
        if (rb < PSLOTS) {
            atomicAdd(&ls[rb], t3);
            atomicAdd(&lc[rb], 1.0f);
        } else {
            atomicAdd(&sums[bF + rb], t3);
            atomicAdd(&cnt[bF + rb], 1.0f);
        }
    }
    __syncthreads();
    for (int i = threadIdx.x; i < PSLOTS; i += blockDim.x) {
        if (lc[i] != 0.f) {
            atomicAdd(&sums[bF + i], ls[i]);
            atomicAdd(&cnt[bF + i], lc[i]);
        }
    }
}

// ---- K8: mean + linear bias + sigmoid ----
__global__ void final_kernel(const float* __restrict__ sums, const float* __restrict__ cnt,
                             const float* __restrict__ coeff, float* __restrict__ out,
                             int ngraphs) {
    int i = blockIdx.x * blockDim.x + threadIdx.x;
    if (i < ngraphs) {
        float m = sums[i] / fmaxf(cnt[i], 1.0f) + coeff[7];
        out[i] = 1.0f / (1.0f + expf(-m));
    }
}

// ======================= fallback (R1 atomic path) =========================
__global__ void fb_coeffs_kernel(const float* __restrict__ W1, const float* __restrict__ b1,
                                 const float* __restrict__ W2, const float* __restrict__ b2,
                                 const float* __restrict__ W3, const float* __restrict__ b3,
                                 const float* __restrict__ lin_w, const float* __restrict__ lin_b,
                                 float* __restrict__ coeff,
                                 float* __restrict__ sums, float* __restrict__ cnt, int ngraphs) {
    for (int i = threadIdx.x; i < ngraphs; i += blockDim.x) { sums[i] = 0.f; cnt[i] = 0.f; }
    if (threadIdx.x == 0) {
        float w3l[16], w2l[16];
        for (int i = 0; i < 16; ++i) {
            float s = 0.f;
            for (int j = 0; j < 16; ++j) s += W3[i * 16 + j] * lin_w[j];
            w3l[i] = s;
        }
        for (int i = 0; i < 16; ++i) {
            float s = 0.f;
            for (int j = 0; j < 16; ++j) s += W2[i * 16 + j] * w3l[j];
            w2l[i] = s;
        }
        for (int i = 0; i < 4; ++i) {
            float s = 0.f;
            for (int j = 0; j < 16; ++j) s += W1[i * 16 + j] * w2l[j];
            coeff[i] = s;
        }
        float s2 = 0.f, s1 = 0.f, s0 = 0.f;
        for (int j = 0; j < 16; ++j) {
            s2 += b1[j] * w2l[j];
            s1 += b2[j] * w3l[j];
            s0 += b3[j] * lin_w[j];
        }
        coeff[4] = s2; coeff[5] = s1; coeff[6] = s0; coeff[7] = lin_b[0];
    }
}
__global__ void fb_init_kernel(float* __restrict__ deg, int n) {
    int i = blockIdx.x * blockDim.x + threadIdx.x;
    int stride = gridDim.x * blockDim.x;
    for (int k = i; k < n; k += stride) deg[k] = 1.0f;
}
__global__ void fb_deg_kernel(const int* __restrict__ col, float* __restrict__ deg, int E) {
    int i = blockIdx.x * blockDim.x + threadIdx.x;
    int stride = gridDim.x * blockDim.x;
    for (int k = i; k < E; k += stride) atomicAdd(&deg[col[k]], 1.0f);
}
__global__ void fb_node0_kernel(const float* __restrict__ x, const float* __restrict__ coeff,
                                float* __restrict__ deg_dinv, float* __restrict__ g,
                                float* __restrict__ acc, int n) {
    int i = blockIdx.x * blockDim.x + threadIdx.x;
    int stride = gridDim.x * blockDim.x;
    for (int k = i; k < n; k += stride) {
        float d = rsqrtf(deg_dinv[k]);
        deg_dinv[k] = d;
        float4 xv = ((const float4*)x)[k];
        float t0 = xv.x * coeff[0] + xv.y * coeff[1] + xv.z * coeff[2] + xv.w * coeff[3];
        g[k] = d * t0;
        acc[k] = 0.f;
    }
}
__global__ void fb_edge_kernel(const int* __restrict__ ei, const float* __restrict__ g,
                               float* __restrict__ acc, int E) {
    int i = blockIdx.x * blockDim.x + threadIdx.x;
    int stride = gridDim.x * blockDim.x;
    for (int k = i; k < E; k += stride) atomicAdd(&acc[ei[E + k]], g[ei[k]]);
}
__global__ void fb_node_kernel(const float* __restrict__ dinv, float* __restrict__ g,
                               float* __restrict__ acc, const float* __restrict__ coeff,
                               int sidx, int n) {
    int i = blockIdx.x * blockDim.x + threadIdx.x;
    int stride = gridDim.x * blockDim.x;
    for (int k = i; k < n; k += stride) {
        float d = dinv[k];
        float t = d * (acc[k] + g[k]) + coeff[sidx];
        g[k] = d * t;
        acc[k] = 0.f;
    }
}
__global__ void fb_pool_kernel(const float* __restrict__ dinv, const float* __restrict__ g,
                               const float* __restrict__ acc, const float* __restrict__ coeff,
                               const int* __restrict__ batch, float* __restrict__ sums,
                               float* __restrict__ cnt, int n) {
    int i = blockIdx.x * blockDim.x + threadIdx.x;
    int stride = gridDim.x * blockDim.x;
    for (int k = i; k < n; k += stride) {
        float d = dinv[k];
        float t3 = d * (acc[k] + g[k]) + coeff[6];
        int b = batch[k];
        atomicAdd(&sums[b], t3);
        atomicAdd(&cnt[b], 1.0f);
    }
}
// ===========================================================================

extern "C" void kernel_launch(void* const* d_in, const int* in_sizes, int n_in,
                              void* d_out, int out_size, void* d_ws, size_t ws_size,
                              hipStream_t stream) {
    const float* x     = (const float*)d_in[0];
    const int*   ei    = (const int*)d_in[1];
    const int*   batch = (const int*)d_in[2];
    const float* W1    = (const float*)d_in[3];
    const float* b1    = (const float*)d_in[4];
    const float* W2    = (const float*)d_in[5];
    const float* b2    = (const float*)d_in[6];
    const float* W3    = (const float*)d_in[7];
    const float* b3    = (const float*)d_in[8];
    const float* lin_w = (const float*)d_in[9];
    const float* lin_b = (const float*)d_in[10];

    const int n       = in_sizes[0] / 4;   // 100000
    const int E       = in_sizes[1] / 2;   // 3200000
    const int ngraphs = out_size;          // 1000

    const int nbuck = (n + BSZ - 1) / BSZ; // 782
    const int B = 256;

    size_t npad  = ((size_t)n + 255) & ~(size_t)255;
    size_t gpad  = ((size_t)ngraphs + 255) & ~(size_t)255;
    size_t nbpad = ((size_t)nbuck + 1 + 255) & ~(size_t)255;
    size_t mlen  = (size_t)NB_SCAT * nbuck;

    size_t need = (256 + mlen + 2 * nbpad + (size_t)E + 3 * npad + 2 * gpad) * 4;

    float* ws    = (float*)d_ws;
    float* coeff = ws;                                    // 256
    unsigned* M        = (unsigned*)(coeff + 256);        // mlen
    unsigned* binTotal = M + mlen;                        // nbpad
    unsigned* bstart   = binTotal + nbpad;                // nbpad
    unsigned* buck     = bstart + nbpad;                  // E (16B aligned)
    float* dinv  = (float*)(buck + E);                    // npad
    float* gA    = dinv + npad;                           // npad
    float* gB    = gA + npad;                             // npad
    float* sums  = gB + npad;                             // gpad
    float* cnt   = sums + gpad;                           // gpad

    bool mainok = (n < (1 << 17)) && nbuck >= 1 && nbuck <= 2048 && ws_size >= need;

    if (!mainok) {
        // -------- fallback: R1 atomic path --------
        float* fcoeff = ws;
        float* deg = fcoeff + 256;
        float* g   = deg + npad;
        float* acc = g + npad;
        float* fsums = acc + npad;
        float* fcnt  = fsums + gpad;
        int nodeBlocks = (n + B - 1) / B;
        int edgeBlocks = (E + B - 1) / B;
        fb_coeffs_kernel<<<1, 64, 0, stream>>>(W1, b1, W2, b2, W3, b3, lin_w, lin_b, fcoeff,
                                               fsums, fcnt, ngraphs);
        fb_init_kernel<<<nodeBlocks, B, 0, stream>>>(deg, n);
        fb_deg_kernel<<<edgeBlocks, B, 0, stream>>>(ei + E, deg, E);
        fb_node0_kernel<<<nodeBlocks, B, 0, stream>>>(x, fcoeff, deg, g, acc, n);
        fb_edge_kernel<<<edgeBlocks, B, 0, stream>>>(ei, g, acc, E);
        fb_node_kernel<<<nodeBlocks, B, 0, stream>>>(deg, g, acc, fcoeff, 4, n);
        fb_edge_kernel<<<edgeBlocks, B, 0, stream>>>(ei, g, acc, E);
        fb_node_kernel<<<nodeBlocks, B, 0, stream>>>(deg, g, acc, fcoeff, 5, n);
        fb_edge_kernel<<<edgeBlocks, B, 0, stream>>>(ei, g, acc, E);
        fb_pool_kernel<<<nodeBlocks, B, 0, stream>>>(deg, g, acc, fcoeff, batch, fsums, fcnt, n);
        final_kernel<<<(ngraphs + B - 1) / B, B, 0, stream>>>(fsums, fcnt, fcoeff, (float*)d_out, ngraphs);
        return;
    }

    int tile = (((E + NB_SCAT - 1) / NB_SCAT) + 3) & ~3;   // multiple of 4
    size_t ldsHist = (size_t)nbuck * sizeof(unsigned);
    size_t ldsScat = (size_t)(2 * nbuck + NB_SCAT) * sizeof(unsigned);

    hist_kernel<<<NB_SCAT, B, ldsHist, stream>>>(ei + E, E, tile, nbuck, M,
                                                 W1, b1, W2, b2, W3, b3, lin_w, lin_b,
                                                 coeff, sums, cnt, ngraphs);
    scanA_kernel<<<nbuck, NB_SCAT, 0, stream>>>(M, binTotal, nbuck);
    scatter_kernel<<<NB_SCAT, B, ldsScat, stream>>>(ei, ei + E, E, tile, nbuck, M,
                                                    binTotal, bstart, buck);

    degnode0_kernel<<<nbuck, BSZ, 0, stream>>>(buck, bstart, x, coeff, dinv, gA, n);
    gather_kernel<<<nbuck, BSZ, 0, stream>>>(buck, bstart, dinv, gA, gB, coeff, 4, n);
    gather_kernel<<<nbuck, BSZ, 0, stream>>>(buck, bstart, dinv, gB, gA, coeff, 5, n);
    gatherpool_kernel<<<nbuck, BSZ, 0, stream>>>(buck, bstart, dinv, gA, coeff, batch,
                                                 sums, cnt, n);

    final_kernel<<<(ngraphs + B - 1) / B, B, 0, stream>>>(sums, cnt, coeff, (float*)d_out, ngraphs);
}